// Round 13
// baseline (454.622 us; speedup 1.0000x reference)
//
#include <hip/hip_runtime.h>

#define NN 100000
#define D 64
#define G 3        // node-range groups (hist/fill)
#define RS 33334   // nodes per range (G*RS >= NN)
#define NC 85      // edge chunks
#define NB (G*NC)  // 255 blocks for hist/fill

typedef short bf16x8 __attribute__((ext_vector_type(8)));
typedef float f32x4 __attribute__((ext_vector_type(4)));

// ---- bf16 helpers ----
__device__ __forceinline__ float bf2f_lo(unsigned w) { return __uint_as_float(w << 16); }
__device__ __forceinline__ float bf2f_hi(unsigned w) { return __uint_as_float(w & 0xffff0000u); }
__device__ __forceinline__ unsigned short f2bf(float f) {
    unsigned u = __float_as_uint(f);
    return (unsigned short)((u + 0x7fffu + ((u >> 16) & 1u)) >> 16);
}
__device__ __forceinline__ unsigned pack2(float a, float b) {
    return (unsigned)f2bf(a) | ((unsigned)f2bf(b) << 16);
}

// ---- byte-packed LDS histogram: word k = nodes 2k,2k+1; per node (src,dst) bytes ----
__global__ __launch_bounds__(1024) void k_hist(const int* __restrict__ src,
                                               const int* __restrict__ dst,
                                               unsigned short* __restrict__ psd, int E) {
    __shared__ unsigned h[RS / 2];
    int b = blockIdx.x, t = threadIdx.x;
    int g = b / NC, c = b - g * NC;
    int lo = g * RS;
    for (int i = t; i < RS / 2; i += 1024) h[i] = 0;
    __syncthreads();
    int e0 = (int)((((long long)c * E / NC)) & ~3LL);
    int e1 = (c == NC - 1) ? E : (int)((((long long)(c + 1) * E / NC)) & ~3LL);
    int m = (e1 - e0) & ~4095;
    for (int e = e0 + t * 4; e < e0 + m; e += 4096) {
        int4 s4 = *(const int4*)(src + e);
        int4 d4 = *(const int4*)(dst + e);
        int v;
        v = s4.x - lo; if ((unsigned)v < RS) atomicAdd(&h[v >> 1], 1u << ((v & 1) * 16));
        v = s4.y - lo; if ((unsigned)v < RS) atomicAdd(&h[v >> 1], 1u << ((v & 1) * 16));
        v = s4.z - lo; if ((unsigned)v < RS) atomicAdd(&h[v >> 1], 1u << ((v & 1) * 16));
        v = s4.w - lo; if ((unsigned)v < RS) atomicAdd(&h[v >> 1], 1u << ((v & 1) * 16));
        v = d4.x - lo; if ((unsigned)v < RS) atomicAdd(&h[v >> 1], 1u << ((v & 1) * 16 + 8));
        v = d4.y - lo; if ((unsigned)v < RS) atomicAdd(&h[v >> 1], 1u << ((v & 1) * 16 + 8));
        v = d4.z - lo; if ((unsigned)v < RS) atomicAdd(&h[v >> 1], 1u << ((v & 1) * 16 + 8));
        v = d4.w - lo; if ((unsigned)v < RS) atomicAdd(&h[v >> 1], 1u << ((v & 1) * 16 + 8));
    }
    for (int e = e0 + m + t; e < e1; e += 1024) {
        int v = src[e] - lo; if ((unsigned)v < RS) atomicAdd(&h[v >> 1], 1u << ((v & 1) * 16));
        v = dst[e] - lo;     if ((unsigned)v < RS) atomicAdd(&h[v >> 1], 1u << ((v & 1) * 16 + 8));
    }
    __syncthreads();
    unsigned* pb = (unsigned*)(psd + (size_t)b * RS);
    for (int i = t; i < RS / 2; i += 1024) pb[i] = h[i];
}

// ---- merge byte partials -> norms; block-scan 1024 in-degrees -> rowptr partial ----
__global__ __launch_bounds__(1024) void k_scan1m(const unsigned short* __restrict__ psd,
                                                 float* __restrict__ ns, float* __restrict__ nd,
                                                 int* __restrict__ rowptr,
                                                 int* __restrict__ bsum, int n) {
    __shared__ int lds[1024];
    int t = threadIdx.x;
    int i = blockIdx.x * 1024 + t;
    int sv = 0, dv = 0;
    if (i < n) {
        int g = i / RS, off = i - g * RS;
        const unsigned short* p = psd + (size_t)(g * NC) * RS + off;
        #pragma unroll 5
        for (int c = 0; c < NC; ++c) {
            unsigned v = p[(size_t)c * RS];
            sv += (int)(v & 0xffu);
            dv += (int)(v >> 8);
        }
        ns[i] = rsqrtf(fmaxf((float)sv, 1.0f));
        nd[i] = rsqrtf(fmaxf((float)dv, 1.0f));
    }
    lds[t] = dv;
    __syncthreads();
    for (int off = 1; off < 1024; off <<= 1) {
        int v = lds[t];
        int a = (t >= off) ? lds[t - off] : 0;
        __syncthreads();
        lds[t] = v + a;
        __syncthreads();
    }
    if (t == 1023) bsum[blockIdx.x] = lds[1023];
    if (i < n) rowptr[i] = lds[t] - dv;   // exclusive
}

// ---- finalize rowptr + write 16-bit within-segment cursors; bsum scan fused ----
__global__ void k_scan3c(int* __restrict__ rowptr, const int* __restrict__ bsum,
                         const unsigned short* __restrict__ psd,
                         unsigned short* __restrict__ cur16,
                         int n, int E, int nb) {
    __shared__ int sbs[128];
    int t = threadIdx.x;
    if (t < 128) sbs[t] = (t < nb) ? bsum[t] : 0;
    __syncthreads();
    for (int off = 1; off < 128; off <<= 1) {
        int v = 0, a = 0;
        if (t < 128) { v = sbs[t]; if (t >= off) a = sbs[t - off]; }
        __syncthreads();
        if (t < 128) sbs[t] = v + a;
        __syncthreads();
    }
    int i = blockIdx.x * blockDim.x + t;
    if (i == 0) rowptr[n] = E;
    if (i >= n) return;
    int blk = i >> 10;
    int base = (blk > 0) ? sbs[blk - 1] : 0;
    int r = rowptr[i] + base;
    rowptr[i] = r;
    int g = i / RS, off = i - g * RS;
    const unsigned short* p = psd + (size_t)(g * NC) * RS + off;
    unsigned short* cp = cur16 + (size_t)(g * NC) * RS + off;
    int run = 0;
    #pragma unroll 5
    for (int c = 0; c < NC; ++c) {
        cp[(size_t)c * RS] = (unsigned short)run;
        run += (int)(p[(size_t)c * RS] >> 8);
    }
}

// ---- counting-sort fill: LDS cursors = rowptr + 16-bit offsets ----
__global__ __launch_bounds__(1024) void k_fillsort(const int* __restrict__ src,
                                                   const int* __restrict__ dst,
                                                   const float* __restrict__ ew,
                                                   const int* __restrict__ rowptr,
                                                   const unsigned short* __restrict__ cur16,
                                                   int2* __restrict__ cw, int E) {
    __shared__ int cur[RS];
    int b = blockIdx.x, t = threadIdx.x;
    int g = b / NC, c = b - g * NC;
    int lo = g * RS;
    const unsigned short* c16 = cur16 + (size_t)b * RS;
    for (int i = t; i < RS; i += 1024) cur[i] = rowptr[lo + i] + (int)c16[i];
    __syncthreads();
    int e0 = (int)((((long long)c * E / NC)) & ~3LL);
    int e1 = (c == NC - 1) ? E : (int)((((long long)(c + 1) * E / NC)) & ~3LL);
    int m = (e1 - e0) & ~4095;
    for (int e = e0 + t * 4; e < e0 + m; e += 4096) {
        int4 s4 = *(const int4*)(src + e);
        int4 d4 = *(const int4*)(dst + e);
        float4 w4 = *(const float4*)(ew + e);
        int d;
        d = d4.x - lo; if ((unsigned)d < RS) { int p = atomicAdd(&cur[d], 1); cw[p] = make_int2(s4.x, __float_as_int(w4.x)); }
        d = d4.y - lo; if ((unsigned)d < RS) { int p = atomicAdd(&cur[d], 1); cw[p] = make_int2(s4.y, __float_as_int(w4.y)); }
        d = d4.z - lo; if ((unsigned)d < RS) { int p = atomicAdd(&cur[d], 1); cw[p] = make_int2(s4.z, __float_as_int(w4.z)); }
        d = d4.w - lo; if ((unsigned)d < RS) { int p = atomicAdd(&cur[d], 1); cw[p] = make_int2(s4.w, __float_as_int(w4.w)); }
    }
    for (int e = e0 + m + t; e < e1; e += 1024) {
        int d = dst[e] - lo;
        if ((unsigned)d < RS) {
            int p = atomicAdd(&cur[d], 1);
            cw[p] = make_int2(src[e], __float_as_int(ew[e]));
        }
    }
}

// ---- xs = bf16(x * norm_s) ----
__global__ void k_scale(const float* __restrict__ x, const float* __restrict__ ns,
                        unsigned short* __restrict__ xsb, int n16) {
    int i = blockIdx.x * blockDim.x + threadIdx.x;
    if (i < n16) {
        float s = ns[i >> 4];
        float4 v = ((const float4*)x)[i];
        ((uint2*)xsb)[i] = make_uint2(pack2(v.x * s, v.y * s), pack2(v.z * s, v.w * s));
    }
}

// ---- split-half gather: task = (node, feature-half of 32 = one 64B line). ----
// Halves pinned to XCD sets via blockIdx%8 round-robin: (b&7)<4 -> half 0.
// Half-wave (32 lanes) per task: 4 edge slots x 8 lanes x 4 feats, 4-edge unroll.
template<bool LAST>
__global__ void k_gather(const int* __restrict__ rowptr, const int2* __restrict__ cw,
                         const unsigned short* __restrict__ tmat,
                         const float* __restrict__ nd, const float* __restrict__ ns,
                         const float* __restrict__ bias,
                         const unsigned short* __restrict__ resb,
                         unsigned short* __restrict__ outb, int n, int E) {
    int b = blockIdx.x;
    int grp = b >> 3, r = b & 7;
    int half = r >> 2, sub = r & 3;          // XCD 0-3 -> half 0, XCD 4-7 -> half 1
    int hw = threadIdx.x >> 5;               // half-wave 0..7
    int node = grp * 32 + sub * 8 + hw;
    int lane = threadIdx.x & 31;
    if (node >= n) return;
    int g = lane >> 3;   // edge slot 0..3
    int h = lane & 7;    // feature quad within half: feats half*32 + 4h .. +3
    const unsigned short* tb = tmat + half * 32;
    int beg = rowptr[node], end = rowptr[node + 1];
    float a0=0,a1=0,a2=0,a3=0;
    float c0=0,c1=0,c2=0,c3=0;
    for (int base = beg; base < end; base += 16) {
        int eA = base + g;
        int eB = eA + 4;
        int eC = eA + 8;
        int eD = eA + 12;
        int2 cvA = cw[min(eA, E - 1)];
        int2 cvB = cw[min(eB, E - 1)];
        int2 cvC = cw[min(eC, E - 1)];
        int2 cvD = cw[min(eD, E - 1)];
        float wA = (eA < end) ? __int_as_float(cvA.y) : 0.f;
        float wB = (eB < end) ? __int_as_float(cvB.y) : 0.f;
        float wC = (eC < end) ? __int_as_float(cvC.y) : 0.f;
        float wD = (eD < end) ? __int_as_float(cvD.y) : 0.f;
        uint2 rA = *((const uint2*)(tb + (size_t)cvA.x * D) + h);
        uint2 rB = *((const uint2*)(tb + (size_t)cvB.x * D) + h);
        uint2 rC = *((const uint2*)(tb + (size_t)cvC.x * D) + h);
        uint2 rD = *((const uint2*)(tb + (size_t)cvD.x * D) + h);
        a0 += wA * bf2f_lo(rA.x); a1 += wA * bf2f_hi(rA.x);
        a2 += wA * bf2f_lo(rA.y); a3 += wA * bf2f_hi(rA.y);
        c0 += wB * bf2f_lo(rB.x); c1 += wB * bf2f_hi(rB.x);
        c2 += wB * bf2f_lo(rB.y); c3 += wB * bf2f_hi(rB.y);
        a0 += wC * bf2f_lo(rC.x); a1 += wC * bf2f_hi(rC.x);
        a2 += wC * bf2f_lo(rC.y); a3 += wC * bf2f_hi(rC.y);
        c0 += wD * bf2f_lo(rD.x); c1 += wD * bf2f_hi(rD.x);
        c2 += wD * bf2f_lo(rD.y); c3 += wD * bf2f_hi(rD.y);
    }
    a0 += c0; a1 += c1; a2 += c2; a3 += c3;
    #pragma unroll
    for (int msk = 8; msk <= 16; msk <<= 1) {
        a0 += __shfl_xor(a0, msk); a1 += __shfl_xor(a1, msk);
        a2 += __shfl_xor(a2, msk); a3 += __shfl_xor(a3, msk);
    }
    float ndv = nd[node];
    int fo = half * 32 + 4 * h;
    float4 bb = *(const float4*)(bias + fo);
    float v0 = ndv * a0 + bb.x, v1 = ndv * a1 + bb.y;
    float v2 = ndv * a2 + bb.z, v3 = ndv * a3 + bb.w;
    if (LAST) {
        uint2 rr = *((const uint2*)(resb + (size_t)node * D + half * 32) + h);
        v0 += bf2f_lo(rr.x); v1 += bf2f_hi(rr.x);
        v2 += bf2f_lo(rr.y); v3 += bf2f_hi(rr.y);
    }
    v0 = fmaxf(v0, 0.f); v1 = fmaxf(v1, 0.f); v2 = fmaxf(v2, 0.f); v3 = fmaxf(v3, 0.f);
    if (!LAST) {
        float s = ns[node];
        v0 *= s; v1 *= s; v2 *= s; v3 *= s;
    }
    if (g == 0) {
        *((uint2*)(outb + (size_t)node * D + half * 32) + h) =
            make_uint2(pack2(v0, v1), pack2(v2, v3));
    }
}

// ---- MFMA node GEMM: 64-node tile/block (4 waves x 16-row strips), K=64 ----
template<int OUTD, bool BIAS, bool IN_BF16, bool OUT_BF16>
__global__ __launch_bounds__(256) void k_gemm(const void* __restrict__ in_,
                                              const float* __restrict__ W,
                                              const float* __restrict__ bias,
                                              void* __restrict__ out_, int n) {
    constexpr int NT = OUTD / 16;   // n-tiles
    __shared__ unsigned short WT[OUTD][72];   // stride 72: <=2-way bank alias (free)
    int t = threadIdx.x;
    for (int i = t; i < 64 * OUTD; i += 256) {
        int k = i / OUTD, nn = i % OUTD;      // W row-major [k][nn], coalesced
        WT[nn][k] = f2bf(W[i]);
    }
    __syncthreads();
    int w = t >> 6, lane = t & 63;
    int m = lane & 15, q = lane >> 4;
    int node0 = blockIdx.x * 64 + w * 16;
    int nodeA = min(node0 + m, n - 1);
    bf16x8 afr[2];
    if (IN_BF16) {
        const unsigned short* inb = (const unsigned short*)in_ + (size_t)nodeA * D;
        #pragma unroll
        for (int kc = 0; kc < 2; ++kc) {
            union { bf16x8 v; uint4 u; } tmp;
            tmp.u = *(const uint4*)(inb + kc * 32 + q * 8);
            afr[kc] = tmp.v;
        }
    } else {
        const float* inf = (const float*)in_ + (size_t)nodeA * D;
        #pragma unroll
        for (int kc = 0; kc < 2; ++kc) {
            float4 f0 = *(const float4*)(inf + kc * 32 + q * 8);
            float4 f1 = *(const float4*)(inf + kc * 32 + q * 8 + 4);
            union { bf16x8 v; unsigned short u[8]; } tmp;
            tmp.u[0] = f2bf(f0.x); tmp.u[1] = f2bf(f0.y);
            tmp.u[2] = f2bf(f0.z); tmp.u[3] = f2bf(f0.w);
            tmp.u[4] = f2bf(f1.x); tmp.u[5] = f2bf(f1.y);
            tmp.u[6] = f2bf(f1.z); tmp.u[7] = f2bf(f1.w);
            afr[kc] = tmp.v;
        }
    }
    #pragma unroll
    for (int nt = 0; nt < NT; ++nt) {
        f32x4 acc = {0.f, 0.f, 0.f, 0.f};
        #pragma unroll
        for (int kc = 0; kc < 2; ++kc) {
            union { bf16x8 v; uint4 u; } bfr;
            bfr.u = *(const uint4*)&WT[nt * 16 + m][kc * 32 + q * 8];
            acc = __builtin_amdgcn_mfma_f32_16x16x32_bf16(afr[kc], bfr.v, acc, 0, 0, 0);
        }
        int col = nt * 16 + m;
        float bb = BIAS ? bias[col] : 0.f;
        #pragma unroll
        for (int r = 0; r < 4; ++r) {
            int node = node0 + q * 4 + r;
            if (node < n) {
                float v = acc[r] + bb;
                if (OUT_BF16)
                    ((unsigned short*)out_)[(size_t)node * OUTD + col] = f2bf(v);
                else
                    ((float*)out_)[(size_t)node * OUTD + col] = v;
            }
        }
    }
}

static inline char* align_up(char* p, size_t a) {
    return (char*)(((uintptr_t)p + a - 1) & ~(uintptr_t)(a - 1));
}

extern "C" void kernel_launch(void* const* d_in, const int* in_sizes, int n_in,
                              void* d_out, int out_size, void* d_ws, size_t ws_size,
                              hipStream_t stream) {
    const float* x   = (const float*)d_in[0];
    const int*   src = (const int*)d_in[1];
    const int*   dst = (const int*)d_in[2];
    const float* ew  = (const float*)d_in[3];
    const float* Wl[4] = {(const float*)d_in[4], (const float*)d_in[6],
                          (const float*)d_in[8], (const float*)d_in[10]};
    const float* bl[4] = {(const float*)d_in[5], (const float*)d_in[7],
                          (const float*)d_in[9], (const float*)d_in[11]};
    const float* Wr = (const float*)d_in[12];
    const float* br = (const float*)d_in[13];
    const float* Wo = (const float*)d_in[14];
    const float* bo = (const float*)d_in[15];
    float* out = (float*)d_out;

    const int N = NN;
    const int E = in_sizes[1];

    // ---- workspace (256B-aligned); total ~61 MB ----
    char* p = (char*)d_ws;
    float* norm_s = (float*)p;            p = align_up(p + N * 4, 256);
    float* norm_d = (float*)p;            p = align_up(p + N * 4, 256);
    int*   rowptr = (int*)p;              p = align_up(p + (size_t)(G * RS + 80) * 4, 256);
    int*   bsum   = (int*)p;              p = align_up(p + 128 * 4, 256);
    int2*  cw     = (int2*)p;             p = align_up(p + (size_t)E * 8, 256);
    unsigned short* psd   = (unsigned short*)p; p = align_up(p + (size_t)NB * RS * 2, 256);
    unsigned short* cur16 = (unsigned short*)p; p = align_up(p + (size_t)NB * RS * 2, 256);
    unsigned short* resb  = (unsigned short*)p; p = align_up(p + (size_t)N * D * 2, 256);
    // aliases: psd+cur16 region (34 MB) holds xs+tmat (25.6) once CSR build is done
    unsigned short* xs   = psd;
    unsigned short* tmat = xs + (size_t)N * D;

    // ---- CSR build (byte partials, 16-bit cursors, 3 edge passes) ----
    k_hist<<<NB, 1024, 0, stream>>>(src, dst, psd, E);
    int nb = (N + 1023) / 1024;  // 98
    k_scan1m<<<nb, 1024, 0, stream>>>(psd, norm_s, norm_d, rowptr, bsum, N);
    k_scan3c<<<(N + 255) / 256, 256, 0, stream>>>(rowptr, bsum, psd, cur16, N, E, nb);
    k_fillsort<<<NB, 1024, 0, stream>>>(src, dst, ew, rowptr, cur16, cw, E);

    // ---- xs = bf16(Ds*X); res = bf16(X @ Wr + br) ----
    k_scale<<<(N * 16 + 255) / 256, 256, 0, stream>>>(x, norm_s, xs, N * 16);
    k_gemm<64, true, false, true><<<(N + 63) / 64, 256, 0, stream>>>(x, Wr, br, resb, N);

    // ---- 4 GCN layers: t = xs@W (MFMA), then split-half gather + epilogue ----
    int ggrid = ((N + 31) / 32) * 8;   // 8 blocks per 32 nodes (4 per feature half)
    for (int l = 0; l < 4; ++l) {
        k_gemm<64, false, true, true><<<(N + 63) / 64, 256, 0, stream>>>(
            xs, Wl[l], nullptr, tmat, N);
        if (l < 3) {
            k_gather<false><<<ggrid, 256, 0, stream>>>(
                rowptr, cw, tmat, norm_d, norm_s, bl[l], nullptr, xs, N, E);
        } else {
            k_gather<true><<<ggrid, 256, 0, stream>>>(
                rowptr, cw, tmat, norm_d, nullptr, bl[l], resb, xs, N, E);
        }
    }
    // ---- out = h4 @ Wo + bo (MFMA) ----
    k_gemm<32, true, true, false><<<(N + 63) / 64, 256, 0, stream>>>(xs, Wo, bo, out, N);
}

// Round 14
// 356.036 us; speedup vs baseline: 1.2769x; 1.2769x over previous
//
#include <hip/hip_runtime.h>

#define NN 100000
#define D 64
#define G 3        // node-range groups (hist/fill)
#define RS 33334   // nodes per range (G*RS >= NN)
#define NC 85      // edge chunks
#define NB (G*NC)  // 255 blocks for hist/fill

typedef short bf16x8 __attribute__((ext_vector_type(8)));
typedef float f32x4 __attribute__((ext_vector_type(4)));

// ---- bf16 helpers ----
__device__ __forceinline__ float bf2f_lo(unsigned w) { return __uint_as_float(w << 16); }
__device__ __forceinline__ float bf2f_hi(unsigned w) { return __uint_as_float(w & 0xffff0000u); }
__device__ __forceinline__ unsigned short f2bf(float f) {
    unsigned u = __float_as_uint(f);
    return (unsigned short)((u + 0x7fffu + ((u >> 16) & 1u)) >> 16);
}
__device__ __forceinline__ unsigned pack2(float a, float b) {
    return (unsigned)f2bf(a) | ((unsigned)f2bf(b) << 16);
}

// ---- byte-packed LDS histogram: word k = nodes 2k,2k+1; per node (src,dst) bytes ----
__global__ __launch_bounds__(1024) void k_hist(const int* __restrict__ src,
                                               const int* __restrict__ dst,
                                               unsigned short* __restrict__ psd, int E) {
    __shared__ unsigned h[RS / 2];
    int b = blockIdx.x, t = threadIdx.x;
    int g = b / NC, c = b - g * NC;
    int lo = g * RS;
    for (int i = t; i < RS / 2; i += 1024) h[i] = 0;
    __syncthreads();
    int e0 = (int)((((long long)c * E / NC)) & ~3LL);
    int e1 = (c == NC - 1) ? E : (int)((((long long)(c + 1) * E / NC)) & ~3LL);
    int m = (e1 - e0) & ~4095;
    for (int e = e0 + t * 4; e < e0 + m; e += 4096) {
        int4 s4 = *(const int4*)(src + e);
        int4 d4 = *(const int4*)(dst + e);
        int v;
        v = s4.x - lo; if ((unsigned)v < RS) atomicAdd(&h[v >> 1], 1u << ((v & 1) * 16));
        v = s4.y - lo; if ((unsigned)v < RS) atomicAdd(&h[v >> 1], 1u << ((v & 1) * 16));
        v = s4.z - lo; if ((unsigned)v < RS) atomicAdd(&h[v >> 1], 1u << ((v & 1) * 16));
        v = s4.w - lo; if ((unsigned)v < RS) atomicAdd(&h[v >> 1], 1u << ((v & 1) * 16));
        v = d4.x - lo; if ((unsigned)v < RS) atomicAdd(&h[v >> 1], 1u << ((v & 1) * 16 + 8));
        v = d4.y - lo; if ((unsigned)v < RS) atomicAdd(&h[v >> 1], 1u << ((v & 1) * 16 + 8));
        v = d4.z - lo; if ((unsigned)v < RS) atomicAdd(&h[v >> 1], 1u << ((v & 1) * 16 + 8));
        v = d4.w - lo; if ((unsigned)v < RS) atomicAdd(&h[v >> 1], 1u << ((v & 1) * 16 + 8));
    }
    for (int e = e0 + m + t; e < e1; e += 1024) {
        int v = src[e] - lo; if ((unsigned)v < RS) atomicAdd(&h[v >> 1], 1u << ((v & 1) * 16));
        v = dst[e] - lo;     if ((unsigned)v < RS) atomicAdd(&h[v >> 1], 1u << ((v & 1) * 16 + 8));
    }
    __syncthreads();
    unsigned* pb = (unsigned*)(psd + (size_t)b * RS);
    for (int i = t; i < RS / 2; i += 1024) pb[i] = h[i];
}

// ---- merge byte partials -> norms; block-scan 1024 in-degrees -> rowptr partial ----
__global__ __launch_bounds__(1024) void k_scan1m(const unsigned short* __restrict__ psd,
                                                 float* __restrict__ ns, float* __restrict__ nd,
                                                 int* __restrict__ rowptr,
                                                 int* __restrict__ bsum, int n) {
    __shared__ int lds[1024];
    int t = threadIdx.x;
    int i = blockIdx.x * 1024 + t;
    int sv = 0, dv = 0;
    if (i < n) {
        int g = i / RS, off = i - g * RS;
        const unsigned short* p = psd + (size_t)(g * NC) * RS + off;
        #pragma unroll 5
        for (int c = 0; c < NC; ++c) {
            unsigned v = p[(size_t)c * RS];
            sv += (int)(v & 0xffu);
            dv += (int)(v >> 8);
        }
        ns[i] = rsqrtf(fmaxf((float)sv, 1.0f));
        nd[i] = rsqrtf(fmaxf((float)dv, 1.0f));
    }
    lds[t] = dv;
    __syncthreads();
    for (int off = 1; off < 1024; off <<= 1) {
        int v = lds[t];
        int a = (t >= off) ? lds[t - off] : 0;
        __syncthreads();
        lds[t] = v + a;
        __syncthreads();
    }
    if (t == 1023) bsum[blockIdx.x] = lds[1023];
    if (i < n) rowptr[i] = lds[t] - dv;   // exclusive
}

// ---- finalize rowptr + write 16-bit within-segment cursors; bsum scan fused ----
__global__ void k_scan3c(int* __restrict__ rowptr, const int* __restrict__ bsum,
                         const unsigned short* __restrict__ psd,
                         unsigned short* __restrict__ cur16,
                         int n, int E, int nb) {
    __shared__ int sbs[128];
    int t = threadIdx.x;
    if (t < 128) sbs[t] = (t < nb) ? bsum[t] : 0;
    __syncthreads();
    for (int off = 1; off < 128; off <<= 1) {
        int v = 0, a = 0;
        if (t < 128) { v = sbs[t]; if (t >= off) a = sbs[t - off]; }
        __syncthreads();
        if (t < 128) sbs[t] = v + a;
        __syncthreads();
    }
    int i = blockIdx.x * blockDim.x + t;
    if (i == 0) rowptr[n] = E;
    if (i >= n) return;
    int blk = i >> 10;
    int base = (blk > 0) ? sbs[blk - 1] : 0;
    int r = rowptr[i] + base;
    rowptr[i] = r;
    int g = i / RS, off = i - g * RS;
    const unsigned short* p = psd + (size_t)(g * NC) * RS + off;
    unsigned short* cp = cur16 + (size_t)(g * NC) * RS + off;
    int run = 0;
    #pragma unroll 5
    for (int c = 0; c < NC; ++c) {
        cp[(size_t)c * RS] = (unsigned short)run;
        run += (int)(p[(size_t)c * RS] >> 8);
    }
}

// ---- counting-sort fill: LDS cursors = rowptr + 16-bit offsets ----
__global__ __launch_bounds__(1024) void k_fillsort(const int* __restrict__ src,
                                                   const int* __restrict__ dst,
                                                   const float* __restrict__ ew,
                                                   const int* __restrict__ rowptr,
                                                   const unsigned short* __restrict__ cur16,
                                                   int2* __restrict__ cw, int E) {
    __shared__ int cur[RS];
    int b = blockIdx.x, t = threadIdx.x;
    int g = b / NC, c = b - g * NC;
    int lo = g * RS;
    const unsigned short* c16 = cur16 + (size_t)b * RS;
    for (int i = t; i < RS; i += 1024) cur[i] = rowptr[lo + i] + (int)c16[i];
    __syncthreads();
    int e0 = (int)((((long long)c * E / NC)) & ~3LL);
    int e1 = (c == NC - 1) ? E : (int)((((long long)(c + 1) * E / NC)) & ~3LL);
    int m = (e1 - e0) & ~4095;
    for (int e = e0 + t * 4; e < e0 + m; e += 4096) {
        int4 s4 = *(const int4*)(src + e);
        int4 d4 = *(const int4*)(dst + e);
        float4 w4 = *(const float4*)(ew + e);
        int d;
        d = d4.x - lo; if ((unsigned)d < RS) { int p = atomicAdd(&cur[d], 1); cw[p] = make_int2(s4.x, __float_as_int(w4.x)); }
        d = d4.y - lo; if ((unsigned)d < RS) { int p = atomicAdd(&cur[d], 1); cw[p] = make_int2(s4.y, __float_as_int(w4.y)); }
        d = d4.z - lo; if ((unsigned)d < RS) { int p = atomicAdd(&cur[d], 1); cw[p] = make_int2(s4.z, __float_as_int(w4.z)); }
        d = d4.w - lo; if ((unsigned)d < RS) { int p = atomicAdd(&cur[d], 1); cw[p] = make_int2(s4.w, __float_as_int(w4.w)); }
    }
    for (int e = e0 + m + t; e < e1; e += 1024) {
        int d = dst[e] - lo;
        if ((unsigned)d < RS) {
            int p = atomicAdd(&cur[d], 1);
            cw[p] = make_int2(src[e], __float_as_int(ew[e]));
        }
    }
}

// ---- gather-reduce + epilogue: HALF-WAVE per node (2 nodes/wave), ----
// ---- 4 edge slots x 8 feat lanes, 4-edge unroll = 16 edges in flight/node ----
template<bool LAST>
__global__ void k_gather(const int* __restrict__ rowptr, const int2* __restrict__ cw,
                         const unsigned short* __restrict__ tmat,
                         const float* __restrict__ nd, const float* __restrict__ ns,
                         const float* __restrict__ bias,
                         const unsigned short* __restrict__ resb,
                         unsigned short* __restrict__ outb, int n, int E) {
    int node = blockIdx.x * (blockDim.x >> 5) + (threadIdx.x >> 5);
    int lane = threadIdx.x & 31;
    if (node >= n) return;
    int g = lane >> 3;   // edge slot 0..3
    int h = lane & 7;    // feature octet
    int beg = rowptr[node], end = rowptr[node + 1];
    float a0=0,a1=0,a2=0,a3=0,a4=0,a5=0,a6=0,a7=0;
    float c0=0,c1=0,c2=0,c3=0,c4=0,c5=0,c6=0,c7=0;
    for (int base = beg; base < end; base += 16) {
        int eA = base + g;
        int eB = eA + 4;
        int eC = eA + 8;
        int eD = eA + 12;
        int2 cvA = cw[min(eA, E - 1)];
        int2 cvB = cw[min(eB, E - 1)];
        int2 cvC = cw[min(eC, E - 1)];
        int2 cvD = cw[min(eD, E - 1)];
        float wA = (eA < end) ? __int_as_float(cvA.y) : 0.f;
        float wB = (eB < end) ? __int_as_float(cvB.y) : 0.f;
        float wC = (eC < end) ? __int_as_float(cvC.y) : 0.f;
        float wD = (eD < end) ? __int_as_float(cvD.y) : 0.f;
        uint4 rA = *((const uint4*)(tmat + (size_t)cvA.x * D) + h);
        uint4 rB = *((const uint4*)(tmat + (size_t)cvB.x * D) + h);
        uint4 rC = *((const uint4*)(tmat + (size_t)cvC.x * D) + h);
        uint4 rD = *((const uint4*)(tmat + (size_t)cvD.x * D) + h);
        a0 += wA * bf2f_lo(rA.x); a1 += wA * bf2f_hi(rA.x);
        a2 += wA * bf2f_lo(rA.y); a3 += wA * bf2f_hi(rA.y);
        a4 += wA * bf2f_lo(rA.z); a5 += wA * bf2f_hi(rA.z);
        a6 += wA * bf2f_lo(rA.w); a7 += wA * bf2f_hi(rA.w);
        c0 += wB * bf2f_lo(rB.x); c1 += wB * bf2f_hi(rB.x);
        c2 += wB * bf2f_lo(rB.y); c3 += wB * bf2f_hi(rB.y);
        c4 += wB * bf2f_lo(rB.z); c5 += wB * bf2f_hi(rB.z);
        c6 += wB * bf2f_lo(rB.w); c7 += wB * bf2f_hi(rB.w);
        a0 += wC * bf2f_lo(rC.x); a1 += wC * bf2f_hi(rC.x);
        a2 += wC * bf2f_lo(rC.y); a3 += wC * bf2f_hi(rC.y);
        a4 += wC * bf2f_lo(rC.z); a5 += wC * bf2f_hi(rC.z);
        a6 += wC * bf2f_lo(rC.w); a7 += wC * bf2f_hi(rC.w);
        c0 += wD * bf2f_lo(rD.x); c1 += wD * bf2f_hi(rD.x);
        c2 += wD * bf2f_lo(rD.y); c3 += wD * bf2f_hi(rD.y);
        c4 += wD * bf2f_lo(rD.z); c5 += wD * bf2f_hi(rD.z);
        c6 += wD * bf2f_lo(rD.w); c7 += wD * bf2f_hi(rD.w);
    }
    a0 += c0; a1 += c1; a2 += c2; a3 += c3;
    a4 += c4; a5 += c5; a6 += c6; a7 += c7;
    #pragma unroll
    for (int msk = 8; msk <= 16; msk <<= 1) {
        a0 += __shfl_xor(a0, msk); a1 += __shfl_xor(a1, msk);
        a2 += __shfl_xor(a2, msk); a3 += __shfl_xor(a3, msk);
        a4 += __shfl_xor(a4, msk); a5 += __shfl_xor(a5, msk);
        a6 += __shfl_xor(a6, msk); a7 += __shfl_xor(a7, msk);
    }
    float ndv = nd[node];
    float4 b0 = *(const float4*)(bias + 8 * h);
    float4 b1 = *(const float4*)(bias + 8 * h + 4);
    float v0 = ndv * a0 + b0.x, v1 = ndv * a1 + b0.y;
    float v2 = ndv * a2 + b0.z, v3 = ndv * a3 + b0.w;
    float v4 = ndv * a4 + b1.x, v5 = ndv * a5 + b1.y;
    float v6 = ndv * a6 + b1.z, v7 = ndv * a7 + b1.w;
    if (LAST) {
        uint4 r = *((const uint4*)(resb + (size_t)node * D) + h);
        v0 += bf2f_lo(r.x); v1 += bf2f_hi(r.x);
        v2 += bf2f_lo(r.y); v3 += bf2f_hi(r.y);
        v4 += bf2f_lo(r.z); v5 += bf2f_hi(r.z);
        v6 += bf2f_lo(r.w); v7 += bf2f_hi(r.w);
    }
    v0 = fmaxf(v0, 0.f); v1 = fmaxf(v1, 0.f); v2 = fmaxf(v2, 0.f); v3 = fmaxf(v3, 0.f);
    v4 = fmaxf(v4, 0.f); v5 = fmaxf(v5, 0.f); v6 = fmaxf(v6, 0.f); v7 = fmaxf(v7, 0.f);
    if (!LAST) {
        float s = ns[node];
        v0 *= s; v1 *= s; v2 *= s; v3 *= s; v4 *= s; v5 *= s; v6 *= s; v7 *= s;
    }
    if (g == 0) {
        uint4 o = make_uint4(pack2(v0, v1), pack2(v2, v3), pack2(v4, v5), pack2(v6, v7));
        *((uint4*)(outb + (size_t)node * D) + h) = o;
    }
}

// ---- MFMA node GEMM: 64-node tile/block (4 waves x 16-row strips), K=64 ----
// SCALE_STORE: also emit xs = bf16(in * ns) from the already-loaded A rows (fp32 path)
template<int OUTD, bool BIAS, bool IN_BF16, bool OUT_BF16, bool SCALE_STORE>
__global__ __launch_bounds__(256) void k_gemm(const void* __restrict__ in_,
                                              const float* __restrict__ W,
                                              const float* __restrict__ bias,
                                              void* __restrict__ out_,
                                              const float* __restrict__ ns,
                                              unsigned short* __restrict__ xs_out,
                                              int n) {
    constexpr int NT = OUTD / 16;   // n-tiles
    __shared__ unsigned short WT[OUTD][72];   // stride 72: <=2-way bank alias (free)
    int t = threadIdx.x;
    for (int i = t; i < 64 * OUTD; i += 256) {
        int k = i / OUTD, nn = i % OUTD;      // W row-major [k][nn], coalesced
        WT[nn][k] = f2bf(W[i]);
    }
    __syncthreads();
    int w = t >> 6, lane = t & 63;
    int m = lane & 15, q = lane >> 4;
    int node0 = blockIdx.x * 64 + w * 16;
    int nodeA = min(node0 + m, n - 1);
    bf16x8 afr[2];
    if (IN_BF16) {
        const unsigned short* inb = (const unsigned short*)in_ + (size_t)nodeA * D;
        #pragma unroll
        for (int kc = 0; kc < 2; ++kc) {
            union { bf16x8 v; uint4 u; } tmp;
            tmp.u = *(const uint4*)(inb + kc * 32 + q * 8);
            afr[kc] = tmp.v;
        }
    } else {
        const float* inf = (const float*)in_ + (size_t)nodeA * D;
        float sc = SCALE_STORE ? ns[nodeA] : 0.f;
        #pragma unroll
        for (int kc = 0; kc < 2; ++kc) {
            float4 f0 = *(const float4*)(inf + kc * 32 + q * 8);
            float4 f1 = *(const float4*)(inf + kc * 32 + q * 8 + 4);
            union { bf16x8 v; unsigned short u[8]; } tmp;
            tmp.u[0] = f2bf(f0.x); tmp.u[1] = f2bf(f0.y);
            tmp.u[2] = f2bf(f0.z); tmp.u[3] = f2bf(f0.w);
            tmp.u[4] = f2bf(f1.x); tmp.u[5] = f2bf(f1.y);
            tmp.u[6] = f2bf(f1.z); tmp.u[7] = f2bf(f1.w);
            afr[kc] = tmp.v;
            if (SCALE_STORE && node0 + m < n) {
                uint2 o = make_uint2(pack2(f0.x * sc, f0.y * sc), pack2(f0.z * sc, f0.w * sc));
                uint2 o2 = make_uint2(pack2(f1.x * sc, f1.y * sc), pack2(f1.z * sc, f1.w * sc));
                *((uint2*)(xs_out + (size_t)nodeA * D + kc * 32 + q * 8)) = o;
                *((uint2*)(xs_out + (size_t)nodeA * D + kc * 32 + q * 8 + 4)) = o2;
            }
        }
    }
    #pragma unroll
    for (int nt = 0; nt < NT; ++nt) {
        f32x4 acc = {0.f, 0.f, 0.f, 0.f};
        #pragma unroll
        for (int kc = 0; kc < 2; ++kc) {
            union { bf16x8 v; uint4 u; } bfr;
            bfr.u = *(const uint4*)&WT[nt * 16 + m][kc * 32 + q * 8];
            acc = __builtin_amdgcn_mfma_f32_16x16x32_bf16(afr[kc], bfr.v, acc, 0, 0, 0);
        }
        int col = nt * 16 + m;
        float bb = BIAS ? bias[col] : 0.f;
        #pragma unroll
        for (int r = 0; r < 4; ++r) {
            int node = node0 + q * 4 + r;
            if (node < n) {
                float v = acc[r] + bb;
                if (OUT_BF16)
                    ((unsigned short*)out_)[(size_t)node * OUTD + col] = f2bf(v);
                else
                    ((float*)out_)[(size_t)node * OUTD + col] = v;
            }
        }
    }
}

static inline char* align_up(char* p, size_t a) {
    return (char*)(((uintptr_t)p + a - 1) & ~(uintptr_t)(a - 1));
}

extern "C" void kernel_launch(void* const* d_in, const int* in_sizes, int n_in,
                              void* d_out, int out_size, void* d_ws, size_t ws_size,
                              hipStream_t stream) {
    const float* x   = (const float*)d_in[0];
    const int*   src = (const int*)d_in[1];
    const int*   dst = (const int*)d_in[2];
    const float* ew  = (const float*)d_in[3];
    const float* Wl[4] = {(const float*)d_in[4], (const float*)d_in[6],
                          (const float*)d_in[8], (const float*)d_in[10]};
    const float* bl[4] = {(const float*)d_in[5], (const float*)d_in[7],
                          (const float*)d_in[9], (const float*)d_in[11]};
    const float* Wr = (const float*)d_in[12];
    const float* br = (const float*)d_in[13];
    const float* Wo = (const float*)d_in[14];
    const float* bo = (const float*)d_in[15];
    float* out = (float*)d_out;

    const int N = NN;
    const int E = in_sizes[1];

    // ---- workspace (256B-aligned); total ~61 MB ----
    char* p = (char*)d_ws;
    float* norm_s = (float*)p;            p = align_up(p + N * 4, 256);
    float* norm_d = (float*)p;            p = align_up(p + N * 4, 256);
    int*   rowptr = (int*)p;              p = align_up(p + (size_t)(G * RS + 80) * 4, 256);
    int*   bsum   = (int*)p;              p = align_up(p + 128 * 4, 256);
    int2*  cw     = (int2*)p;             p = align_up(p + (size_t)E * 8, 256);
    unsigned short* psd   = (unsigned short*)p; p = align_up(p + (size_t)NB * RS * 2, 256);
    unsigned short* cur16 = (unsigned short*)p; p = align_up(p + (size_t)NB * RS * 2, 256);
    unsigned short* resb  = (unsigned short*)p; p = align_up(p + (size_t)N * D * 2, 256);
    // aliases: psd+cur16 region (34 MB) holds xs+tmat (25.6) once CSR build is done
    unsigned short* xs   = psd;
    unsigned short* tmat = xs + (size_t)N * D;

    // ---- CSR build (byte partials, 16-bit cursors, 3 edge passes) ----
    k_hist<<<NB, 1024, 0, stream>>>(src, dst, psd, E);
    int nb = (N + 1023) / 1024;  // 98
    k_scan1m<<<nb, 1024, 0, stream>>>(psd, norm_s, norm_d, rowptr, bsum, N);
    k_scan3c<<<(N + 255) / 256, 256, 0, stream>>>(rowptr, bsum, psd, cur16, N, E, nb);
    k_fillsort<<<NB, 1024, 0, stream>>>(src, dst, ew, rowptr, cur16, cw, E);

    // ---- res = bf16(X @ Wr + br) fused with xs = bf16(Ds*X) store ----
    k_gemm<64, true, false, true, true><<<(N + 63) / 64, 256, 0, stream>>>(
        x, Wr, br, resb, norm_s, xs, N);

    // ---- 4 GCN layers: t = xs@W (assoc. swap, MFMA), then gather+epilogue ----
    for (int l = 0; l < 4; ++l) {
        k_gemm<64, false, true, true, false><<<(N + 63) / 64, 256, 0, stream>>>(
            xs, Wl[l], nullptr, tmat, nullptr, nullptr, N);
        if (l < 3) {
            k_gather<false><<<(N + 7) / 8, 256, 0, stream>>>(
                rowptr, cw, tmat, norm_d, norm_s, bl[l], nullptr, xs, N, E);
        } else {
            k_gather<true><<<(N + 7) / 8, 256, 0, stream>>>(
                rowptr, cw, tmat, norm_d, nullptr, bl[l], resb, xs, N, E);
        }
    }
    // ---- out = h4 @ Wo + bo (MFMA) ----
    k_gemm<32, true, true, false, false><<<(N + 63) / 64, 256, 0, stream>>>(
        xs, Wo, bo, out, nullptr, nullptr, N);
}

// Round 15
// 344.010 us; speedup vs baseline: 1.3215x; 1.0350x over previous
//
#include <hip/hip_runtime.h>

#define NN 100000
#define D 64
#define G 3        // node-range groups (hist/fill)
#define RS 33334   // nodes per range (G*RS >= NN)
#define NC 85      // edge chunks
#define NB (G*NC)  // 255 blocks for hist/fill

typedef short bf16x8 __attribute__((ext_vector_type(8)));
typedef float f32x4 __attribute__((ext_vector_type(4)));
typedef float f32x2 __attribute__((ext_vector_type(2)));

// ---- bf16 helpers ----
__device__ __forceinline__ float bf2f_lo(unsigned w) { return __uint_as_float(w << 16); }
__device__ __forceinline__ float bf2f_hi(unsigned w) { return __uint_as_float(w & 0xffff0000u); }
__device__ __forceinline__ unsigned short f2bf(float f) {
    unsigned u = __float_as_uint(f);
    return (unsigned short)((u + 0x7fffu + ((u >> 16) & 1u)) >> 16);
}
__device__ __forceinline__ unsigned pack2(float a, float b) {
    return (unsigned)f2bf(a) | ((unsigned)f2bf(b) << 16);
}
// ---- fp8 e4m3 helpers (HW cvt) ----
__device__ __forceinline__ unsigned char f2fp8(float v) {
    return (unsigned char)(__builtin_amdgcn_cvt_pk_fp8_f32(v, v, 0, false) & 0xff);
}

// ---- byte-packed LDS histogram: word k = nodes 2k,2k+1; per node (src,dst) bytes ----
__global__ __launch_bounds__(1024) void k_hist(const int* __restrict__ src,
                                               const int* __restrict__ dst,
                                               unsigned short* __restrict__ psd, int E) {
    __shared__ unsigned h[RS / 2];
    int b = blockIdx.x, t = threadIdx.x;
    int g = b / NC, c = b - g * NC;
    int lo = g * RS;
    for (int i = t; i < RS / 2; i += 1024) h[i] = 0;
    __syncthreads();
    int e0 = (int)((((long long)c * E / NC)) & ~3LL);
    int e1 = (c == NC - 1) ? E : (int)((((long long)(c + 1) * E / NC)) & ~3LL);
    int m = (e1 - e0) & ~4095;
    for (int e = e0 + t * 4; e < e0 + m; e += 4096) {
        int4 s4 = *(const int4*)(src + e);
        int4 d4 = *(const int4*)(dst + e);
        int v;
        v = s4.x - lo; if ((unsigned)v < RS) atomicAdd(&h[v >> 1], 1u << ((v & 1) * 16));
        v = s4.y - lo; if ((unsigned)v < RS) atomicAdd(&h[v >> 1], 1u << ((v & 1) * 16));
        v = s4.z - lo; if ((unsigned)v < RS) atomicAdd(&h[v >> 1], 1u << ((v & 1) * 16));
        v = s4.w - lo; if ((unsigned)v < RS) atomicAdd(&h[v >> 1], 1u << ((v & 1) * 16));
        v = d4.x - lo; if ((unsigned)v < RS) atomicAdd(&h[v >> 1], 1u << ((v & 1) * 16 + 8));
        v = d4.y - lo; if ((unsigned)v < RS) atomicAdd(&h[v >> 1], 1u << ((v & 1) * 16 + 8));
        v = d4.z - lo; if ((unsigned)v < RS) atomicAdd(&h[v >> 1], 1u << ((v & 1) * 16 + 8));
        v = d4.w - lo; if ((unsigned)v < RS) atomicAdd(&h[v >> 1], 1u << ((v & 1) * 16 + 8));
    }
    for (int e = e0 + m + t; e < e1; e += 1024) {
        int v = src[e] - lo; if ((unsigned)v < RS) atomicAdd(&h[v >> 1], 1u << ((v & 1) * 16));
        v = dst[e] - lo;     if ((unsigned)v < RS) atomicAdd(&h[v >> 1], 1u << ((v & 1) * 16 + 8));
    }
    __syncthreads();
    unsigned* pb = (unsigned*)(psd + (size_t)b * RS);
    for (int i = t; i < RS / 2; i += 1024) pb[i] = h[i];
}

// ---- merge byte partials -> norms; block-scan 1024 in-degrees -> rowptr partial ----
__global__ __launch_bounds__(1024) void k_scan1m(const unsigned short* __restrict__ psd,
                                                 float* __restrict__ ns, float* __restrict__ nd,
                                                 int* __restrict__ rowptr,
                                                 int* __restrict__ bsum, int n) {
    __shared__ int lds[1024];
    int t = threadIdx.x;
    int i = blockIdx.x * 1024 + t;
    int sv = 0, dv = 0;
    if (i < n) {
        int g = i / RS, off = i - g * RS;
        const unsigned short* p = psd + (size_t)(g * NC) * RS + off;
        #pragma unroll 5
        for (int c = 0; c < NC; ++c) {
            unsigned v = p[(size_t)c * RS];
            sv += (int)(v & 0xffu);
            dv += (int)(v >> 8);
        }
        ns[i] = rsqrtf(fmaxf((float)sv, 1.0f));
        nd[i] = rsqrtf(fmaxf((float)dv, 1.0f));
    }
    lds[t] = dv;
    __syncthreads();
    for (int off = 1; off < 1024; off <<= 1) {
        int v = lds[t];
        int a = (t >= off) ? lds[t - off] : 0;
        __syncthreads();
        lds[t] = v + a;
        __syncthreads();
    }
    if (t == 1023) bsum[blockIdx.x] = lds[1023];
    if (i < n) rowptr[i] = lds[t] - dv;   // exclusive
}

// ---- finalize rowptr + write 16-bit within-segment cursors; bsum scan fused ----
__global__ void k_scan3c(int* __restrict__ rowptr, const int* __restrict__ bsum,
                         const unsigned short* __restrict__ psd,
                         unsigned short* __restrict__ cur16,
                         int n, int E, int nb) {
    __shared__ int sbs[128];
    int t = threadIdx.x;
    if (t < 128) sbs[t] = (t < nb) ? bsum[t] : 0;
    __syncthreads();
    for (int off = 1; off < 128; off <<= 1) {
        int v = 0, a = 0;
        if (t < 128) { v = sbs[t]; if (t >= off) a = sbs[t - off]; }
        __syncthreads();
        if (t < 128) sbs[t] = v + a;
        __syncthreads();
    }
    int i = blockIdx.x * blockDim.x + t;
    if (i == 0) rowptr[n] = E;
    if (i >= n) return;
    int blk = i >> 10;
    int base = (blk > 0) ? sbs[blk - 1] : 0;
    int r = rowptr[i] + base;
    rowptr[i] = r;
    int g = i / RS, off = i - g * RS;
    const unsigned short* p = psd + (size_t)(g * NC) * RS + off;
    unsigned short* cp = cur16 + (size_t)(g * NC) * RS + off;
    int run = 0;
    #pragma unroll 5
    for (int c = 0; c < NC; ++c) {
        cp[(size_t)c * RS] = (unsigned short)run;
        run += (int)(p[(size_t)c * RS] >> 8);
    }
}

// ---- counting-sort fill: LDS cursors = rowptr + 16-bit offsets ----
__global__ __launch_bounds__(1024) void k_fillsort(const int* __restrict__ src,
                                                   const int* __restrict__ dst,
                                                   const float* __restrict__ ew,
                                                   const int* __restrict__ rowptr,
                                                   const unsigned short* __restrict__ cur16,
                                                   int2* __restrict__ cw, int E) {
    __shared__ int cur[RS];
    int b = blockIdx.x, t = threadIdx.x;
    int g = b / NC, c = b - g * NC;
    int lo = g * RS;
    const unsigned short* c16 = cur16 + (size_t)b * RS;
    for (int i = t; i < RS; i += 1024) cur[i] = rowptr[lo + i] + (int)c16[i];
    __syncthreads();
    int e0 = (int)((((long long)c * E / NC)) & ~3LL);
    int e1 = (c == NC - 1) ? E : (int)((((long long)(c + 1) * E / NC)) & ~3LL);
    int m = (e1 - e0) & ~4095;
    for (int e = e0 + t * 4; e < e0 + m; e += 4096) {
        int4 s4 = *(const int4*)(src + e);
        int4 d4 = *(const int4*)(dst + e);
        float4 w4 = *(const float4*)(ew + e);
        int d;
        d = d4.x - lo; if ((unsigned)d < RS) { int p = atomicAdd(&cur[d], 1); cw[p] = make_int2(s4.x, __float_as_int(w4.x)); }
        d = d4.y - lo; if ((unsigned)d < RS) { int p = atomicAdd(&cur[d], 1); cw[p] = make_int2(s4.y, __float_as_int(w4.y)); }
        d = d4.z - lo; if ((unsigned)d < RS) { int p = atomicAdd(&cur[d], 1); cw[p] = make_int2(s4.z, __float_as_int(w4.z)); }
        d = d4.w - lo; if ((unsigned)d < RS) { int p = atomicAdd(&cur[d], 1); cw[p] = make_int2(s4.w, __float_as_int(w4.w)); }
    }
    for (int e = e0 + m + t; e < e1; e += 1024) {
        int d = dst[e] - lo;
        if ((unsigned)d < RS) {
            int p = atomicAdd(&cur[d], 1);
            cw[p] = make_int2(src[e], __float_as_int(ew[e]));
        }
    }
}

// ---- gather-reduce + epilogue: HALF-WAVE per node (2 nodes/wave), ----
// ---- tmat rows are fp8 e4m3 (64 B/row); 4 edge slots x 8 lanes, 4-edge unroll ----
template<bool LAST>
__global__ void k_gather(const int* __restrict__ rowptr, const int2* __restrict__ cw,
                         const unsigned char* __restrict__ tmat,
                         const float* __restrict__ nd, const float* __restrict__ ns,
                         const float* __restrict__ bias,
                         const unsigned short* __restrict__ resb,
                         unsigned short* __restrict__ outb, int n, int E) {
    int node = blockIdx.x * (blockDim.x >> 5) + (threadIdx.x >> 5);
    int lane = threadIdx.x & 31;
    if (node >= n) return;
    int g = lane >> 3;   // edge slot 0..3
    int h = lane & 7;    // feature octet
    int beg = rowptr[node], end = rowptr[node + 1];
    float a0=0,a1=0,a2=0,a3=0,a4=0,a5=0,a6=0,a7=0;
    float c0=0,c1=0,c2=0,c3=0,c4=0,c5=0,c6=0,c7=0;
    for (int base = beg; base < end; base += 16) {
        int eA = base + g;
        int eB = eA + 4;
        int eC = eA + 8;
        int eD = eA + 12;
        int2 cvA = cw[min(eA, E - 1)];
        int2 cvB = cw[min(eB, E - 1)];
        int2 cvC = cw[min(eC, E - 1)];
        int2 cvD = cw[min(eD, E - 1)];
        float wA = (eA < end) ? __int_as_float(cvA.y) : 0.f;
        float wB = (eB < end) ? __int_as_float(cvB.y) : 0.f;
        float wC = (eC < end) ? __int_as_float(cvC.y) : 0.f;
        float wD = (eD < end) ? __int_as_float(cvD.y) : 0.f;
        uint2 rA = *((const uint2*)(tmat + (size_t)cvA.x * D) + h);
        uint2 rB = *((const uint2*)(tmat + (size_t)cvB.x * D) + h);
        uint2 rC = *((const uint2*)(tmat + (size_t)cvC.x * D) + h);
        uint2 rD = *((const uint2*)(tmat + (size_t)cvD.x * D) + h);
        f32x2 p0, p1, p2, p3;
        p0 = __builtin_amdgcn_cvt_pk_f32_fp8(rA.x, false);
        p1 = __builtin_amdgcn_cvt_pk_f32_fp8(rA.x, true);
        p2 = __builtin_amdgcn_cvt_pk_f32_fp8(rA.y, false);
        p3 = __builtin_amdgcn_cvt_pk_f32_fp8(rA.y, true);
        a0 += wA * p0.x; a1 += wA * p0.y; a2 += wA * p1.x; a3 += wA * p1.y;
        a4 += wA * p2.x; a5 += wA * p2.y; a6 += wA * p3.x; a7 += wA * p3.y;
        p0 = __builtin_amdgcn_cvt_pk_f32_fp8(rB.x, false);
        p1 = __builtin_amdgcn_cvt_pk_f32_fp8(rB.x, true);
        p2 = __builtin_amdgcn_cvt_pk_f32_fp8(rB.y, false);
        p3 = __builtin_amdgcn_cvt_pk_f32_fp8(rB.y, true);
        c0 += wB * p0.x; c1 += wB * p0.y; c2 += wB * p1.x; c3 += wB * p1.y;
        c4 += wB * p2.x; c5 += wB * p2.y; c6 += wB * p3.x; c7 += wB * p3.y;
        p0 = __builtin_amdgcn_cvt_pk_f32_fp8(rC.x, false);
        p1 = __builtin_amdgcn_cvt_pk_f32_fp8(rC.x, true);
        p2 = __builtin_amdgcn_cvt_pk_f32_fp8(rC.y, false);
        p3 = __builtin_amdgcn_cvt_pk_f32_fp8(rC.y, true);
        a0 += wC * p0.x; a1 += wC * p0.y; a2 += wC * p1.x; a3 += wC * p1.y;
        a4 += wC * p2.x; a5 += wC * p2.y; a6 += wC * p3.x; a7 += wC * p3.y;
        p0 = __builtin_amdgcn_cvt_pk_f32_fp8(rD.x, false);
        p1 = __builtin_amdgcn_cvt_pk_f32_fp8(rD.x, true);
        p2 = __builtin_amdgcn_cvt_pk_f32_fp8(rD.y, false);
        p3 = __builtin_amdgcn_cvt_pk_f32_fp8(rD.y, true);
        c0 += wD * p0.x; c1 += wD * p0.y; c2 += wD * p1.x; c3 += wD * p1.y;
        c4 += wD * p2.x; c5 += wD * p2.y; c6 += wD * p3.x; c7 += wD * p3.y;
    }
    a0 += c0; a1 += c1; a2 += c2; a3 += c3;
    a4 += c4; a5 += c5; a6 += c6; a7 += c7;
    #pragma unroll
    for (int msk = 8; msk <= 16; msk <<= 1) {
        a0 += __shfl_xor(a0, msk); a1 += __shfl_xor(a1, msk);
        a2 += __shfl_xor(a2, msk); a3 += __shfl_xor(a3, msk);
        a4 += __shfl_xor(a4, msk); a5 += __shfl_xor(a5, msk);
        a6 += __shfl_xor(a6, msk); a7 += __shfl_xor(a7, msk);
    }
    float ndv = nd[node];
    float4 b0 = *(const float4*)(bias + 8 * h);
    float4 b1 = *(const float4*)(bias + 8 * h + 4);
    float v0 = ndv * a0 + b0.x, v1 = ndv * a1 + b0.y;
    float v2 = ndv * a2 + b0.z, v3 = ndv * a3 + b0.w;
    float v4 = ndv * a4 + b1.x, v5 = ndv * a5 + b1.y;
    float v6 = ndv * a6 + b1.z, v7 = ndv * a7 + b1.w;
    if (LAST) {
        uint4 r = *((const uint4*)(resb + (size_t)node * D) + h);
        v0 += bf2f_lo(r.x); v1 += bf2f_hi(r.x);
        v2 += bf2f_lo(r.y); v3 += bf2f_hi(r.y);
        v4 += bf2f_lo(r.z); v5 += bf2f_hi(r.z);
        v6 += bf2f_lo(r.w); v7 += bf2f_hi(r.w);
    }
    v0 = fmaxf(v0, 0.f); v1 = fmaxf(v1, 0.f); v2 = fmaxf(v2, 0.f); v3 = fmaxf(v3, 0.f);
    v4 = fmaxf(v4, 0.f); v5 = fmaxf(v5, 0.f); v6 = fmaxf(v6, 0.f); v7 = fmaxf(v7, 0.f);
    if (!LAST) {
        float s = ns[node];
        v0 *= s; v1 *= s; v2 *= s; v3 *= s; v4 *= s; v5 *= s; v6 *= s; v7 *= s;
    }
    if (g == 0) {
        uint4 o = make_uint4(pack2(v0, v1), pack2(v2, v3), pack2(v4, v5), pack2(v6, v7));
        *((uint4*)(outb + (size_t)node * D) + h) = o;
    }
}

// ---- MFMA node GEMM: 64-node tile/block (4 waves x 16-row strips), K=64 ----
// OUTMODE: 0=f32, 1=bf16, 2=fp8(e4m3)
// SCALE_STORE: also emit xs = bf16(in * ns) from the already-loaded A rows (fp32 path)
template<int OUTD, bool BIAS, bool IN_BF16, int OUTMODE, bool SCALE_STORE>
__global__ __launch_bounds__(256) void k_gemm(const void* __restrict__ in_,
                                              const float* __restrict__ W,
                                              const float* __restrict__ bias,
                                              void* __restrict__ out_,
                                              const float* __restrict__ ns,
                                              unsigned short* __restrict__ xs_out,
                                              int n) {
    constexpr int NT = OUTD / 16;   // n-tiles
    __shared__ unsigned short WT[OUTD][72];   // stride 72: <=2-way bank alias (free)
    int t = threadIdx.x;
    for (int i = t; i < 64 * OUTD; i += 256) {
        int k = i / OUTD, nn = i % OUTD;      // W row-major [k][nn], coalesced
        WT[nn][k] = f2bf(W[i]);
    }
    __syncthreads();
    int w = t >> 6, lane = t & 63;
    int m = lane & 15, q = lane >> 4;
    int node0 = blockIdx.x * 64 + w * 16;
    int nodeA = min(node0 + m, n - 1);
    bf16x8 afr[2];
    if (IN_BF16) {
        const unsigned short* inb = (const unsigned short*)in_ + (size_t)nodeA * D;
        #pragma unroll
        for (int kc = 0; kc < 2; ++kc) {
            union { bf16x8 v; uint4 u; } tmp;
            tmp.u = *(const uint4*)(inb + kc * 32 + q * 8);
            afr[kc] = tmp.v;
        }
    } else {
        const float* inf = (const float*)in_ + (size_t)nodeA * D;
        float sc = SCALE_STORE ? ns[nodeA] : 0.f;
        #pragma unroll
        for (int kc = 0; kc < 2; ++kc) {
            float4 f0 = *(const float4*)(inf + kc * 32 + q * 8);
            float4 f1 = *(const float4*)(inf + kc * 32 + q * 8 + 4);
            union { bf16x8 v; unsigned short u[8]; } tmp;
            tmp.u[0] = f2bf(f0.x); tmp.u[1] = f2bf(f0.y);
            tmp.u[2] = f2bf(f0.z); tmp.u[3] = f2bf(f0.w);
            tmp.u[4] = f2bf(f1.x); tmp.u[5] = f2bf(f1.y);
            tmp.u[6] = f2bf(f1.z); tmp.u[7] = f2bf(f1.w);
            afr[kc] = tmp.v;
            if (SCALE_STORE && node0 + m < n) {
                uint2 o = make_uint2(pack2(f0.x * sc, f0.y * sc), pack2(f0.z * sc, f0.w * sc));
                uint2 o2 = make_uint2(pack2(f1.x * sc, f1.y * sc), pack2(f1.z * sc, f1.w * sc));
                *((uint2*)(xs_out + (size_t)nodeA * D + kc * 32 + q * 8)) = o;
                *((uint2*)(xs_out + (size_t)nodeA * D + kc * 32 + q * 8 + 4)) = o2;
            }
        }
    }
    #pragma unroll
    for (int nt = 0; nt < NT; ++nt) {
        f32x4 acc = {0.f, 0.f, 0.f, 0.f};
        #pragma unroll
        for (int kc = 0; kc < 2; ++kc) {
            union { bf16x8 v; uint4 u; } bfr;
            bfr.u = *(const uint4*)&WT[nt * 16 + m][kc * 32 + q * 8];
            acc = __builtin_amdgcn_mfma_f32_16x16x32_bf16(afr[kc], bfr.v, acc, 0, 0, 0);
        }
        int col = nt * 16 + m;
        float bb = BIAS ? bias[col] : 0.f;
        #pragma unroll
        for (int r = 0; r < 4; ++r) {
            int node = node0 + q * 4 + r;
            if (node < n) {
                float v = acc[r] + bb;
                if (OUTMODE == 2)
                    ((unsigned char*)out_)[(size_t)node * OUTD + col] = f2fp8(v);
                else if (OUTMODE == 1)
                    ((unsigned short*)out_)[(size_t)node * OUTD + col] = f2bf(v);
                else
                    ((float*)out_)[(size_t)node * OUTD + col] = v;
            }
        }
    }
}

static inline char* align_up(char* p, size_t a) {
    return (char*)(((uintptr_t)p + a - 1) & ~(uintptr_t)(a - 1));
}

extern "C" void kernel_launch(void* const* d_in, const int* in_sizes, int n_in,
                              void* d_out, int out_size, void* d_ws, size_t ws_size,
                              hipStream_t stream) {
    const float* x   = (const float*)d_in[0];
    const int*   src = (const int*)d_in[1];
    const int*   dst = (const int*)d_in[2];
    const float* ew  = (const float*)d_in[3];
    const float* Wl[4] = {(const float*)d_in[4], (const float*)d_in[6],
                          (const float*)d_in[8], (const float*)d_in[10]};
    const float* bl[4] = {(const float*)d_in[5], (const float*)d_in[7],
                          (const float*)d_in[9], (const float*)d_in[11]};
    const float* Wr = (const float*)d_in[12];
    const float* br = (const float*)d_in[13];
    const float* Wo = (const float*)d_in[14];
    const float* bo = (const float*)d_in[15];
    float* out = (float*)d_out;

    const int N = NN;
    const int E = in_sizes[1];

    // ---- workspace (256B-aligned); total ~61 MB ----
    char* p = (char*)d_ws;
    float* norm_s = (float*)p;            p = align_up(p + N * 4, 256);
    float* norm_d = (float*)p;            p = align_up(p + N * 4, 256);
    int*   rowptr = (int*)p;              p = align_up(p + (size_t)(G * RS + 80) * 4, 256);
    int*   bsum   = (int*)p;              p = align_up(p + 128 * 4, 256);
    int2*  cw     = (int2*)p;             p = align_up(p + (size_t)E * 8, 256);
    unsigned short* psd   = (unsigned short*)p; p = align_up(p + (size_t)NB * RS * 2, 256);
    unsigned short* cur16 = (unsigned short*)p; p = align_up(p + (size_t)NB * RS * 2, 256);
    unsigned short* resb  = (unsigned short*)p; p = align_up(p + (size_t)N * D * 2, 256);
    // aliases: psd+cur16 region (34 MB) holds xs (bf16, 12.8) + tmat (fp8, 6.4)
    unsigned short* xs   = psd;
    unsigned char*  tmat = (unsigned char*)(xs + (size_t)N * D);

    // ---- CSR build (byte partials, 16-bit cursors, 3 edge passes) ----
    k_hist<<<NB, 1024, 0, stream>>>(src, dst, psd, E);
    int nb = (N + 1023) / 1024;  // 98
    k_scan1m<<<nb, 1024, 0, stream>>>(psd, norm_s, norm_d, rowptr, bsum, N);
    k_scan3c<<<(N + 255) / 256, 256, 0, stream>>>(rowptr, bsum, psd, cur16, N, E, nb);
    k_fillsort<<<NB, 1024, 0, stream>>>(src, dst, ew, rowptr, cur16, cw, E);

    // ---- res = bf16(X @ Wr + br) fused with xs = bf16(Ds*X) store ----
    k_gemm<64, true, false, 1, true><<<(N + 63) / 64, 256, 0, stream>>>(
        x, Wr, br, resb, norm_s, xs, N);

    // ---- 4 GCN layers: t = fp8(xs@W) (MFMA), then gather+epilogue ----
    for (int l = 0; l < 4; ++l) {
        k_gemm<64, false, true, 2, false><<<(N + 63) / 64, 256, 0, stream>>>(
            xs, Wl[l], nullptr, tmat, nullptr, nullptr, N);
        if (l < 3) {
            k_gather<false><<<(N + 7) / 8, 256, 0, stream>>>(
                rowptr, cw, tmat, norm_d, norm_s, bl[l], nullptr, xs, N, E);
        } else {
            k_gather<true><<<(N + 7) / 8, 256, 0, stream>>>(
                rowptr, cw, tmat, norm_d, nullptr, bl[l], resb, xs, N, E);
        }
    }
    // ---- out = h4 @ Wo + bo (MFMA) ----
    k_gemm<32, true, true, 0, false><<<(N + 63) / 64, 256, 0, stream>>>(
        xs, Wo, bo, out, nullptr, nullptr, N);
}

// Round 16
// 334.534 us; speedup vs baseline: 1.3590x; 1.0283x over previous
//
#include <hip/hip_runtime.h>

#define NN 100000
#define D 64
#define G 3        // node-range groups (hist/fill)
#define RS 33334   // nodes per range (G*RS >= NN)
#define NC 85      // edge chunks
#define NB (G*NC)  // 255 blocks for hist/fill

typedef short bf16x8 __attribute__((ext_vector_type(8)));
typedef float f32x4 __attribute__((ext_vector_type(4)));
typedef float f32x2 __attribute__((ext_vector_type(2)));

// ---- bf16 helpers ----
__device__ __forceinline__ float bf2f_lo(unsigned w) { return __uint_as_float(w << 16); }
__device__ __forceinline__ float bf2f_hi(unsigned w) { return __uint_as_float(w & 0xffff0000u); }
__device__ __forceinline__ unsigned short f2bf(float f) {
    unsigned u = __float_as_uint(f);
    return (unsigned short)((u + 0x7fffu + ((u >> 16) & 1u)) >> 16);
}
__device__ __forceinline__ unsigned pack2(float a, float b) {
    return (unsigned)f2bf(a) | ((unsigned)f2bf(b) << 16);
}
// ---- fp8 e4m3 helpers (HW cvt) ----
__device__ __forceinline__ unsigned char f2fp8(float v) {
    return (unsigned char)(__builtin_amdgcn_cvt_pk_fp8_f32(v, v, 0, false) & 0xff);
}
// ---- packed edge record: bits 0-16 = src, bits 17-31 = bf16(w) sans sign ----
__device__ __forceinline__ unsigned pack_cw(int s, float w) {
    return ((unsigned)f2bf(w) << 17) | (unsigned)s;
}

// ---- byte-packed LDS histogram: word k = nodes 2k,2k+1; per node (src,dst) bytes ----
__global__ __launch_bounds__(1024) void k_hist(const int* __restrict__ src,
                                               const int* __restrict__ dst,
                                               unsigned short* __restrict__ psd, int E) {
    __shared__ unsigned h[RS / 2];
    int b = blockIdx.x, t = threadIdx.x;
    int g = b / NC, c = b - g * NC;
    int lo = g * RS;
    for (int i = t; i < RS / 2; i += 1024) h[i] = 0;
    __syncthreads();
    int e0 = (int)((((long long)c * E / NC)) & ~3LL);
    int e1 = (c == NC - 1) ? E : (int)((((long long)(c + 1) * E / NC)) & ~3LL);
    int m = (e1 - e0) & ~4095;
    for (int e = e0 + t * 4; e < e0 + m; e += 4096) {
        int4 s4 = *(const int4*)(src + e);
        int4 d4 = *(const int4*)(dst + e);
        int v;
        v = s4.x - lo; if ((unsigned)v < RS) atomicAdd(&h[v >> 1], 1u << ((v & 1) * 16));
        v = s4.y - lo; if ((unsigned)v < RS) atomicAdd(&h[v >> 1], 1u << ((v & 1) * 16));
        v = s4.z - lo; if ((unsigned)v < RS) atomicAdd(&h[v >> 1], 1u << ((v & 1) * 16));
        v = s4.w - lo; if ((unsigned)v < RS) atomicAdd(&h[v >> 1], 1u << ((v & 1) * 16));
        v = d4.x - lo; if ((unsigned)v < RS) atomicAdd(&h[v >> 1], 1u << ((v & 1) * 16 + 8));
        v = d4.y - lo; if ((unsigned)v < RS) atomicAdd(&h[v >> 1], 1u << ((v & 1) * 16 + 8));
        v = d4.z - lo; if ((unsigned)v < RS) atomicAdd(&h[v >> 1], 1u << ((v & 1) * 16 + 8));
        v = d4.w - lo; if ((unsigned)v < RS) atomicAdd(&h[v >> 1], 1u << ((v & 1) * 16 + 8));
    }
    for (int e = e0 + m + t; e < e1; e += 1024) {
        int v = src[e] - lo; if ((unsigned)v < RS) atomicAdd(&h[v >> 1], 1u << ((v & 1) * 16));
        v = dst[e] - lo;     if ((unsigned)v < RS) atomicAdd(&h[v >> 1], 1u << ((v & 1) * 16 + 8));
    }
    __syncthreads();
    unsigned* pb = (unsigned*)(psd + (size_t)b * RS);
    for (int i = t; i < RS / 2; i += 1024) pb[i] = h[i];
}

// ---- merge byte partials -> norms; block-scan 1024 in-degrees -> rowptr partial ----
__global__ __launch_bounds__(1024) void k_scan1m(const unsigned short* __restrict__ psd,
                                                 float* __restrict__ ns, float* __restrict__ nd,
                                                 int* __restrict__ rowptr,
                                                 int* __restrict__ bsum, int n) {
    __shared__ int lds[1024];
    int t = threadIdx.x;
    int i = blockIdx.x * 1024 + t;
    int sv = 0, dv = 0;
    if (i < n) {
        int g = i / RS, off = i - g * RS;
        const unsigned short* p = psd + (size_t)(g * NC) * RS + off;
        #pragma unroll 5
        for (int c = 0; c < NC; ++c) {
            unsigned v = p[(size_t)c * RS];
            sv += (int)(v & 0xffu);
            dv += (int)(v >> 8);
        }
        ns[i] = rsqrtf(fmaxf((float)sv, 1.0f));
        nd[i] = rsqrtf(fmaxf((float)dv, 1.0f));
    }
    lds[t] = dv;
    __syncthreads();
    for (int off = 1; off < 1024; off <<= 1) {
        int v = lds[t];
        int a = (t >= off) ? lds[t - off] : 0;
        __syncthreads();
        lds[t] = v + a;
        __syncthreads();
    }
    if (t == 1023) bsum[blockIdx.x] = lds[1023];
    if (i < n) rowptr[i] = lds[t] - dv;   // exclusive
}

// ---- finalize rowptr + write 16-bit within-segment cursors; bsum scan fused ----
__global__ void k_scan3c(int* __restrict__ rowptr, const int* __restrict__ bsum,
                         const unsigned short* __restrict__ psd,
                         unsigned short* __restrict__ cur16,
                         int n, int E, int nb) {
    __shared__ int sbs[128];
    int t = threadIdx.x;
    if (t < 128) sbs[t] = (t < nb) ? bsum[t] : 0;
    __syncthreads();
    for (int off = 1; off < 128; off <<= 1) {
        int v = 0, a = 0;
        if (t < 128) { v = sbs[t]; if (t >= off) a = sbs[t - off]; }
        __syncthreads();
        if (t < 128) sbs[t] = v + a;
        __syncthreads();
    }
    int i = blockIdx.x * blockDim.x + t;
    if (i == 0) rowptr[n] = E;
    if (i >= n) return;
    int blk = i >> 10;
    int base = (blk > 0) ? sbs[blk - 1] : 0;
    int r = rowptr[i] + base;
    rowptr[i] = r;
    int g = i / RS, off = i - g * RS;
    const unsigned short* p = psd + (size_t)(g * NC) * RS + off;
    unsigned short* cp = cur16 + (size_t)(g * NC) * RS + off;
    int run = 0;
    #pragma unroll 5
    for (int c = 0; c < NC; ++c) {
        cp[(size_t)c * RS] = (unsigned short)run;
        run += (int)(p[(size_t)c * RS] >> 8);
    }
}

// ---- counting-sort fill: LDS cursors = rowptr + 16-bit offsets; 4B packed records ----
__global__ __launch_bounds__(1024) void k_fillsort(const int* __restrict__ src,
                                                   const int* __restrict__ dst,
                                                   const float* __restrict__ ew,
                                                   const int* __restrict__ rowptr,
                                                   const unsigned short* __restrict__ cur16,
                                                   unsigned* __restrict__ cw, int E) {
    __shared__ int cur[RS];
    int b = blockIdx.x, t = threadIdx.x;
    int g = b / NC, c = b - g * NC;
    int lo = g * RS;
    const unsigned short* c16 = cur16 + (size_t)b * RS;
    for (int i = t; i < RS; i += 1024) cur[i] = rowptr[lo + i] + (int)c16[i];
    __syncthreads();
    int e0 = (int)((((long long)c * E / NC)) & ~3LL);
    int e1 = (c == NC - 1) ? E : (int)((((long long)(c + 1) * E / NC)) & ~3LL);
    int m = (e1 - e0) & ~4095;
    for (int e = e0 + t * 4; e < e0 + m; e += 4096) {
        int4 s4 = *(const int4*)(src + e);
        int4 d4 = *(const int4*)(dst + e);
        float4 w4 = *(const float4*)(ew + e);
        int d;
        d = d4.x - lo; if ((unsigned)d < RS) { int p = atomicAdd(&cur[d], 1); cw[p] = pack_cw(s4.x, w4.x); }
        d = d4.y - lo; if ((unsigned)d < RS) { int p = atomicAdd(&cur[d], 1); cw[p] = pack_cw(s4.y, w4.y); }
        d = d4.z - lo; if ((unsigned)d < RS) { int p = atomicAdd(&cur[d], 1); cw[p] = pack_cw(s4.z, w4.z); }
        d = d4.w - lo; if ((unsigned)d < RS) { int p = atomicAdd(&cur[d], 1); cw[p] = pack_cw(s4.w, w4.w); }
    }
    for (int e = e0 + m + t; e < e1; e += 1024) {
        int d = dst[e] - lo;
        if ((unsigned)d < RS) {
            int p = atomicAdd(&cur[d], 1);
            cw[p] = pack_cw(src[e], ew[e]);
        }
    }
}

// ---- gather-reduce + epilogue: HALF-WAVE per node (2 nodes/wave), ----
// ---- fp8 tmat rows (64 B), 4B packed cw; 4 edge slots x 8 lanes, 4-edge unroll ----
template<bool LAST>
__global__ void k_gather(const int* __restrict__ rowptr, const unsigned* __restrict__ cw,
                         const unsigned char* __restrict__ tmat,
                         const float* __restrict__ nd, const float* __restrict__ ns,
                         const float* __restrict__ bias,
                         const unsigned short* __restrict__ resb,
                         unsigned short* __restrict__ outb, int n, int E) {
    int node = blockIdx.x * (blockDim.x >> 5) + (threadIdx.x >> 5);
    int lane = threadIdx.x & 31;
    if (node >= n) return;
    int g = lane >> 3;   // edge slot 0..3
    int h = lane & 7;    // feature octet
    int beg = rowptr[node], end = rowptr[node + 1];
    float a0=0,a1=0,a2=0,a3=0,a4=0,a5=0,a6=0,a7=0;
    float c0=0,c1=0,c2=0,c3=0,c4=0,c5=0,c6=0,c7=0;
    for (int base = beg; base < end; base += 16) {
        int eA = base + g;
        int eB = eA + 4;
        int eC = eA + 8;
        int eD = eA + 12;
        unsigned cvA = cw[min(eA, E - 1)];
        unsigned cvB = cw[min(eB, E - 1)];
        unsigned cvC = cw[min(eC, E - 1)];
        unsigned cvD = cw[min(eD, E - 1)];
        float wA = (eA < end) ? __uint_as_float((cvA >> 17) << 16) : 0.f;
        float wB = (eB < end) ? __uint_as_float((cvB >> 17) << 16) : 0.f;
        float wC = (eC < end) ? __uint_as_float((cvC >> 17) << 16) : 0.f;
        float wD = (eD < end) ? __uint_as_float((cvD >> 17) << 16) : 0.f;
        uint2 rA = *((const uint2*)(tmat + (size_t)(cvA & 0x1FFFFu) * D) + h);
        uint2 rB = *((const uint2*)(tmat + (size_t)(cvB & 0x1FFFFu) * D) + h);
        uint2 rC = *((const uint2*)(tmat + (size_t)(cvC & 0x1FFFFu) * D) + h);
        uint2 rD = *((const uint2*)(tmat + (size_t)(cvD & 0x1FFFFu) * D) + h);
        f32x2 p0, p1, p2, p3;
        p0 = __builtin_amdgcn_cvt_pk_f32_fp8(rA.x, false);
        p1 = __builtin_amdgcn_cvt_pk_f32_fp8(rA.x, true);
        p2 = __builtin_amdgcn_cvt_pk_f32_fp8(rA.y, false);
        p3 = __builtin_amdgcn_cvt_pk_f32_fp8(rA.y, true);
        a0 += wA * p0.x; a1 += wA * p0.y; a2 += wA * p1.x; a3 += wA * p1.y;
        a4 += wA * p2.x; a5 += wA * p2.y; a6 += wA * p3.x; a7 += wA * p3.y;
        p0 = __builtin_amdgcn_cvt_pk_f32_fp8(rB.x, false);
        p1 = __builtin_amdgcn_cvt_pk_f32_fp8(rB.x, true);
        p2 = __builtin_amdgcn_cvt_pk_f32_fp8(rB.y, false);
        p3 = __builtin_amdgcn_cvt_pk_f32_fp8(rB.y, true);
        c0 += wB * p0.x; c1 += wB * p0.y; c2 += wB * p1.x; c3 += wB * p1.y;
        c4 += wB * p2.x; c5 += wB * p2.y; c6 += wB * p3.x; c7 += wB * p3.y;
        p0 = __builtin_amdgcn_cvt_pk_f32_fp8(rC.x, false);
        p1 = __builtin_amdgcn_cvt_pk_f32_fp8(rC.x, true);
        p2 = __builtin_amdgcn_cvt_pk_f32_fp8(rC.y, false);
        p3 = __builtin_amdgcn_cvt_pk_f32_fp8(rC.y, true);
        a0 += wC * p0.x; a1 += wC * p0.y; a2 += wC * p1.x; a3 += wC * p1.y;
        a4 += wC * p2.x; a5 += wC * p2.y; a6 += wC * p3.x; a7 += wC * p3.y;
        p0 = __builtin_amdgcn_cvt_pk_f32_fp8(rD.x, false);
        p1 = __builtin_amdgcn_cvt_pk_f32_fp8(rD.x, true);
        p2 = __builtin_amdgcn_cvt_pk_f32_fp8(rD.y, false);
        p3 = __builtin_amdgcn_cvt_pk_f32_fp8(rD.y, true);
        c0 += wD * p0.x; c1 += wD * p0.y; c2 += wD * p1.x; c3 += wD * p1.y;
        c4 += wD * p2.x; c5 += wD * p2.y; c6 += wD * p3.x; c7 += wD * p3.y;
    }
    a0 += c0; a1 += c1; a2 += c2; a3 += c3;
    a4 += c4; a5 += c5; a6 += c6; a7 += c7;
    #pragma unroll
    for (int msk = 8; msk <= 16; msk <<= 1) {
        a0 += __shfl_xor(a0, msk); a1 += __shfl_xor(a1, msk);
        a2 += __shfl_xor(a2, msk); a3 += __shfl_xor(a3, msk);
        a4 += __shfl_xor(a4, msk); a5 += __shfl_xor(a5, msk);
        a6 += __shfl_xor(a6, msk); a7 += __shfl_xor(a7, msk);
    }
    float ndv = nd[node];
    float4 b0 = *(const float4*)(bias + 8 * h);
    float4 b1 = *(const float4*)(bias + 8 * h + 4);
    float v0 = ndv * a0 + b0.x, v1 = ndv * a1 + b0.y;
    float v2 = ndv * a2 + b0.z, v3 = ndv * a3 + b0.w;
    float v4 = ndv * a4 + b1.x, v5 = ndv * a5 + b1.y;
    float v6 = ndv * a6 + b1.z, v7 = ndv * a7 + b1.w;
    if (LAST) {
        uint4 r = *((const uint4*)(resb + (size_t)node * D) + h);
        v0 += bf2f_lo(r.x); v1 += bf2f_hi(r.x);
        v2 += bf2f_lo(r.y); v3 += bf2f_hi(r.y);
        v4 += bf2f_lo(r.z); v5 += bf2f_hi(r.z);
        v6 += bf2f_lo(r.w); v7 += bf2f_hi(r.w);
    }
    v0 = fmaxf(v0, 0.f); v1 = fmaxf(v1, 0.f); v2 = fmaxf(v2, 0.f); v3 = fmaxf(v3, 0.f);
    v4 = fmaxf(v4, 0.f); v5 = fmaxf(v5, 0.f); v6 = fmaxf(v6, 0.f); v7 = fmaxf(v7, 0.f);
    if (!LAST) {
        float s = ns[node];
        v0 *= s; v1 *= s; v2 *= s; v3 *= s; v4 *= s; v5 *= s; v6 *= s; v7 *= s;
    }
    if (g == 0) {
        uint4 o = make_uint4(pack2(v0, v1), pack2(v2, v3), pack2(v4, v5), pack2(v6, v7));
        *((uint4*)(outb + (size_t)node * D) + h) = o;
    }
}

// ---- MFMA node GEMM: 64-node tile/block (4 waves x 16-row strips), K=64 ----
// OUTMODE: 0=f32, 1=bf16, 2=fp8(e4m3)
// SCALE_STORE: also emit xs = bf16(in * ns) from the already-loaded A rows (fp32 path)
template<int OUTD, bool BIAS, bool IN_BF16, int OUTMODE, bool SCALE_STORE>
__global__ __launch_bounds__(256) void k_gemm(const void* __restrict__ in_,
                                              const float* __restrict__ W,
                                              const float* __restrict__ bias,
                                              void* __restrict__ out_,
                                              const float* __restrict__ ns,
                                              unsigned short* __restrict__ xs_out,
                                              int n) {
    constexpr int NT = OUTD / 16;   // n-tiles
    __shared__ unsigned short WT[OUTD][72];   // stride 72: <=2-way bank alias (free)
    int t = threadIdx.x;
    for (int i = t; i < 64 * OUTD; i += 256) {
        int k = i / OUTD, nn = i % OUTD;      // W row-major [k][nn], coalesced
        WT[nn][k] = f2bf(W[i]);
    }
    __syncthreads();
    int w = t >> 6, lane = t & 63;
    int m = lane & 15, q = lane >> 4;
    int node0 = blockIdx.x * 64 + w * 16;
    int nodeA = min(node0 + m, n - 1);
    bf16x8 afr[2];
    if (IN_BF16) {
        const unsigned short* inb = (const unsigned short*)in_ + (size_t)nodeA * D;
        #pragma unroll
        for (int kc = 0; kc < 2; ++kc) {
            union { bf16x8 v; uint4 u; } tmp;
            tmp.u = *(const uint4*)(inb + kc * 32 + q * 8);
            afr[kc] = tmp.v;
        }
    } else {
        const float* inf = (const float*)in_ + (size_t)nodeA * D;
        float sc = SCALE_STORE ? ns[nodeA] : 0.f;
        #pragma unroll
        for (int kc = 0; kc < 2; ++kc) {
            float4 f0 = *(const float4*)(inf + kc * 32 + q * 8);
            float4 f1 = *(const float4*)(inf + kc * 32 + q * 8 + 4);
            union { bf16x8 v; unsigned short u[8]; } tmp;
            tmp.u[0] = f2bf(f0.x); tmp.u[1] = f2bf(f0.y);
            tmp.u[2] = f2bf(f0.z); tmp.u[3] = f2bf(f0.w);
            tmp.u[4] = f2bf(f1.x); tmp.u[5] = f2bf(f1.y);
            tmp.u[6] = f2bf(f1.z); tmp.u[7] = f2bf(f1.w);
            afr[kc] = tmp.v;
            if (SCALE_STORE && node0 + m < n) {
                uint2 o = make_uint2(pack2(f0.x * sc, f0.y * sc), pack2(f0.z * sc, f0.w * sc));
                uint2 o2 = make_uint2(pack2(f1.x * sc, f1.y * sc), pack2(f1.z * sc, f1.w * sc));
                *((uint2*)(xs_out + (size_t)nodeA * D + kc * 32 + q * 8)) = o;
                *((uint2*)(xs_out + (size_t)nodeA * D + kc * 32 + q * 8 + 4)) = o2;
            }
        }
    }
    #pragma unroll
    for (int nt = 0; nt < NT; ++nt) {
        f32x4 acc = {0.f, 0.f, 0.f, 0.f};
        #pragma unroll
        for (int kc = 0; kc < 2; ++kc) {
            union { bf16x8 v; uint4 u; } bfr;
            bfr.u = *(const uint4*)&WT[nt * 16 + m][kc * 32 + q * 8];
            acc = __builtin_amdgcn_mfma_f32_16x16x32_bf16(afr[kc], bfr.v, acc, 0, 0, 0);
        }
        int col = nt * 16 + m;
        float bb = BIAS ? bias[col] : 0.f;
        #pragma unroll
        for (int r = 0; r < 4; ++r) {
            int node = node0 + q * 4 + r;
            if (node < n) {
                float v = acc[r] + bb;
                if (OUTMODE == 2)
                    ((unsigned char*)out_)[(size_t)node * OUTD + col] = f2fp8(v);
                else if (OUTMODE == 1)
                    ((unsigned short*)out_)[(size_t)node * OUTD + col] = f2bf(v);
                else
                    ((float*)out_)[(size_t)node * OUTD + col] = v;
            }
        }
    }
}

static inline char* align_up(char* p, size_t a) {
    return (char*)(((uintptr_t)p + a - 1) & ~(uintptr_t)(a - 1));
}

extern "C" void kernel_launch(void* const* d_in, const int* in_sizes, int n_in,
                              void* d_out, int out_size, void* d_ws, size_t ws_size,
                              hipStream_t stream) {
    const float* x   = (const float*)d_in[0];
    const int*   src = (const int*)d_in[1];
    const int*   dst = (const int*)d_in[2];
    const float* ew  = (const float*)d_in[3];
    const float* Wl[4] = {(const float*)d_in[4], (const float*)d_in[6],
                          (const float*)d_in[8], (const float*)d_in[10]};
    const float* bl[4] = {(const float*)d_in[5], (const float*)d_in[7],
                          (const float*)d_in[9], (const float*)d_in[11]};
    const float* Wr = (const float*)d_in[12];
    const float* br = (const float*)d_in[13];
    const float* Wo = (const float*)d_in[14];
    const float* bo = (const float*)d_in[15];
    float* out = (float*)d_out;

    const int N = NN;
    const int E = in_sizes[1];

    // ---- workspace (256B-aligned); total ~55 MB ----
    char* p = (char*)d_ws;
    float* norm_s = (float*)p;            p = align_up(p + N * 4, 256);
    float* norm_d = (float*)p;            p = align_up(p + N * 4, 256);
    int*   rowptr = (int*)p;              p = align_up(p + (size_t)(G * RS + 80) * 4, 256);
    int*   bsum   = (int*)p;              p = align_up(p + 128 * 4, 256);
    unsigned* cw  = (unsigned*)p;         p = align_up(p + (size_t)E * 4, 256);
    unsigned short* psd   = (unsigned short*)p; p = align_up(p + (size_t)NB * RS * 2, 256);
    unsigned short* cur16 = (unsigned short*)p; p = align_up(p + (size_t)NB * RS * 2, 256);
    unsigned short* resb  = (unsigned short*)p; p = align_up(p + (size_t)N * D * 2, 256);
    // aliases: psd+cur16 region (34 MB) holds xs (bf16, 12.8) + tmat (fp8, 6.4)
    unsigned short* xs   = psd;
    unsigned char*  tmat = (unsigned char*)(xs + (size_t)N * D);

    // ---- CSR build (byte partials, 16-bit cursors, 3 edge passes) ----
    k_hist<<<NB, 1024, 0, stream>>>(src, dst, psd, E);
    int nb = (N + 1023) / 1024;  // 98
    k_scan1m<<<nb, 1024, 0, stream>>>(psd, norm_s, norm_d, rowptr, bsum, N);
    k_scan3c<<<(N + 255) / 256, 256, 0, stream>>>(rowptr, bsum, psd, cur16, N, E, nb);
    k_fillsort<<<NB, 1024, 0, stream>>>(src, dst, ew, rowptr, cur16, cw, E);

    // ---- res = bf16(X @ Wr + br) fused with xs = bf16(Ds*X) store ----
    k_gemm<64, true, false, 1, true><<<(N + 63) / 64, 256, 0, stream>>>(
        x, Wr, br, resb, norm_s, xs, N);

    // ---- 4 GCN layers: t = fp8(xs@W) (MFMA), then gather+epilogue ----
    for (int l = 0; l < 4; ++l) {
        k_gemm<64, false, true, 2, false><<<(N + 63) / 64, 256, 0, stream>>>(
            xs, Wl[l], nullptr, tmat, nullptr, nullptr, N);
        if (l < 3) {
            k_gather<false><<<(N + 7) / 8, 256, 0, stream>>>(
                rowptr, cw, tmat, norm_d, norm_s, bl[l], nullptr, xs, N, E);
        } else {
            k_gather<true><<<(N + 7) / 8, 256, 0, stream>>>(
                rowptr, cw, tmat, norm_d, nullptr, bl[l], resb, xs, N, E);
        }
    }
    // ---- out = h4 @ Wo + bo (MFMA) ----
    k_gemm<32, true, true, 0, false><<<(N + 63) / 64, 256, 0, stream>>>(
        xs, Wo, bo, out, nullptr, nullptr, N);
}